// Round 5
// baseline (414.317 us; speedup 1.0000x reference)
//
#include <hip/hip_runtime.h>

// ---------------------------------------------------------------------------
// Fused MultiHeadAttention forward for MI355X (gfx950).  Round 10.
//   B=4, S=2048, D_MODEL=1024, H=16, depth=64
// Round-10 changes:
//  - cvt3 DELETED.  gemm_qkv now reads the raw fp32 activations directly:
//    A is staged fp32 into LDS (128x64 fp32 = 32KB, 8 GLDS16/wave/iter,
//    16-chunk XOR swizzle), fragments read as 2x ds_read_b128 fp32 and
//    converted to bf16 in-register (VALU was 13% busy - free).  Saves the
//    full 144MB cvt3 memory pass (~28us) + a launch.
//  - attn / gemm_wo / mask_prepack / cvt_weights unchanged from round 9
//    (attn measured 96.4us; round-8 accounting says its dbuf variant is
//    ~neutral, so not worth a slot).
// ---------------------------------------------------------------------------

typedef __bf16 bf16_t;
typedef __bf16 bf16x4 __attribute__((ext_vector_type(4)));
typedef __bf16 bf16x8 __attribute__((ext_vector_type(8)));
typedef float floatx2 __attribute__((ext_vector_type(2)));
typedef float floatx4 __attribute__((ext_vector_type(4)));
typedef float floatx16 __attribute__((ext_vector_type(16)));

#define DMODEL 1024
#define NHEAD  16
#define DEPTH  64
#define BATCH  4
#define SEQ    2048
#define MROWS  (BATCH * SEQ)   // 8192

// exp(s) = exp2(s*log2e); fold log2(e)/8 into Wq (and bq) so QK^T is exp2-ready
#define QSCALE 0.18033688011112042f

#define GLDS16(gaddr, laddr)                                                   \
  __builtin_amdgcn_global_load_lds(                                            \
      (__attribute__((address_space(1))) void*)(gaddr),                        \
      (__attribute__((address_space(3))) void*)(laddr), 16, 0, 0)

// ---------------------------------------------------------------------------
// fp32 -> bf16 for the 4 weight matrices, Wq pre-scaled by QSCALE.
// ---------------------------------------------------------------------------
__global__ __launch_bounds__(256) void cvt_weights(
    const float* __restrict__ w0, const float* __restrict__ w1,
    const float* __restrict__ w2, const float* __restrict__ w3,
    bf16_t* __restrict__ out) {
  const int n_per4 = (DMODEL * DMODEL) / 4;
  int idx = blockIdx.x * blockDim.x + threadIdx.x;
  int t = idx / n_per4;
  int e4 = idx - t * n_per4;
  const float* src = (t == 0) ? w0 : (t == 1) ? w1 : (t == 2) ? w2 : w3;
  const float sc = (t == 0) ? QSCALE : 1.0f;
  float4 v = ((const float4*)src)[e4];
  bf16_t* dst = out + (size_t)t * (DMODEL * DMODEL) + (size_t)e4 * 4;
  dst[0] = (bf16_t)(v.x * sc); dst[1] = (bf16_t)(v.y * sc);
  dst[2] = (bf16_t)(v.z * sc); dst[3] = (bf16_t)(v.w * sc);
}

// ---------------------------------------------------------------------------
// Mask -> per-lane u32 KEEP-bit words (bit=1 means keep) matched to the
// swapped-QK^T 32x32x16 C layout with permuted-K staging:
//   word[((b*64 + g)*32 + it)*64 + lane]:
//     q  = g*32 + (lane&31),  hi = lane>>5
//     bit (kb*16 + r) = 1 iff
//       m_in[b][q][ it*64 + kb*32 + 16*(r>>3) + 8*hi + 4*((r>>2)&1) + (r&3) ]
//       == 0
// ---------------------------------------------------------------------------
__global__ __launch_bounds__(256) void mask_prepack(
    const float* __restrict__ m, unsigned int* __restrict__ M32) {
  size_t t = (size_t)blockIdx.x * blockDim.x + threadIdx.x;  // 4*64*32*64
  int lane = (int)(t & 63);
  int it = (int)((t >> 6) & 31);
  int g  = (int)((t >> 11) & 63);
  int b  = (int)(t >> 17);
  int q  = g * 32 + (lane & 31);
  int hi = lane >> 5;
  const float* row = m + ((size_t)b * SEQ + q) * SEQ + it * 64;
  unsigned int bits = 0;
#pragma unroll
  for (int kb = 0; kb < 2; kb++) {
#pragma unroll
    for (int rc = 0; rc < 4; rc++) {  // rc = r>>2
      const int base = kb * 32 + 16 * (rc >> 1) + 8 * hi + 4 * (rc & 1);
      const float4 mv = *(const float4*)(row + base);
      const int bit0 = kb * 16 + rc * 4;
      if (mv.x == 0.f) bits |= 1u << (bit0 + 0);
      if (mv.y == 0.f) bits |= 1u << (bit0 + 1);
      if (mv.z == 0.f) bits |= 1u << (bit0 + 2);
      if (mv.w == 0.f) bits |= 1u << (bit0 + 3);
    }
  }
  M32[t] = bits;
}

// ---------------------------------------------------------------------------
// Merged QKV GEMM, BK=64, fp32-A fused conversion.
// z = blockIdx.z selects (fp32 input, bf16 weight, bias, output).
// A staged fp32 (32KB LDS, 16-chunk XOR swizzle); fragments cvt'd to bf16
// in-register.  B (weights) staged bf16 as before.  Two-barrier skeleton.
// z<2 -> bf16 out [B,H,S,64] (Q,K); z==2 -> bf16 out [B,H,64,S] (V^T).
// ---------------------------------------------------------------------------
__global__ __launch_bounds__(256) void gemm_qkv(
    const float* __restrict__ Aq, const float* __restrict__ Ak,
    const float* __restrict__ Av, const bf16_t* __restrict__ Wbf,
    const float* __restrict__ bq, const float* __restrict__ bk,
    const float* __restrict__ bv, bf16_t* __restrict__ Qh,
    bf16_t* __restrict__ Kh, bf16_t* __restrict__ Vth) {
  __shared__ __align__(16) float  Asf[128 * 64];  // 32 KB fp32 A tile
  __shared__ __align__(16) bf16_t Bs[128 * 64];   // 16 KB bf16 B tile
  const int K = DMODEL;
  const int tid = threadIdx.x;
  const int lane = tid & 63;
  const int w = tid >> 6;
  const int quad = lane >> 4;
  const int l16 = lane & 15;
  const int wm = w & 1, wn = w >> 1;
  const int z = blockIdx.z;

  const float* A = (z == 0) ? Aq : (z == 1) ? Ak : Av;
  const bf16_t* Bt = Wbf + (size_t)z * DMODEL * DMODEL;
  const float* bias = (z == 0) ? bq : (z == 1) ? bk : bv;
  const float bias_scale = (z == 0) ? QSCALE : 1.0f;
  bf16_t* Ov = (z == 0) ? Qh : (z == 1) ? Kh : Vth;

  const int lin = blockIdx.x + 8 * blockIdx.y;   // (8,64) per z
  const int c = lin & 7;
  const int j = lin >> 3;            // 0..63
  const int n0 = (j & 7) * 128;
  const int m0 = ((j >> 3) * 8 + c) * 128;

  // ---- A staging (fp32): 8 calls/wave, each 4 rows x 256B.
  //  LDS[lr][c_lds] = global[lr][c_lds ^ (lr&15)]  (16B chunks, 16/row)
  const int c16 = lane & 15;
  const int r4 = lane >> 4;
  const float* AgP[8];
#pragma unroll
  for (int cl = 0; cl < 8; cl++) {
    const int lr = w * 32 + cl * 4 + r4;           // local row 0..127
    const int cs = c16 ^ ((cl * 4 + r4) & 15);     // swizzled source chunk
    AgP[cl] = A + (size_t)(m0 + lr) * K + cs * 4;
  }
  // ---- B staging (bf16): 4 calls/wave, each 8 rows x 128B.
  //  LDS[lr][c_lds] = global[lr][c_lds ^ (lr&7)]  (16B chunks, 8/row)
  const int r8l = lane >> 3;
  const int c8l = (lane & 7) ^ r8l;
  const bf16_t* Bg = Bt + (size_t)(n0 + w * 32 + r8l) * K + c8l * 8;
  char* AsB = (char*)Asf + (w * 32) * 256;
  char* BsB = (char*)Bs + (w * 32) * 128;

  floatx4 acc[4][4] = {};

  for (int kk = 0; kk < K; kk += 64) {
    __syncthreads();
#pragma unroll
    for (int cl = 0; cl < 8; cl++)
      GLDS16(AgP[cl] + kk, AsB + cl * 1024);
#pragma unroll
    for (int cl = 0; cl < 4; cl++)
      GLDS16(Bg + kk + (size_t)(cl * 8) * K, BsB + cl * 8 * 128);
    __syncthreads();

#pragma unroll
    for (int kk2 = 0; kk2 < 2; kk2++) {
      bf16x8 af[4], bfr[4];
#pragma unroll
      for (int mi = 0; mi < 4; mi++) {
        const char* Arow = (const char*)Asf + (wm * 64 + mi * 16 + l16) * 256;
        const int cg = kk2 * 8 + quad * 2;
        floatx4 a0 = *(const floatx4*)(Arow + ((cg ^ l16) * 16));
        floatx4 a1 = *(const floatx4*)(Arow + (((cg + 1) ^ l16) * 16));
#pragma unroll
        for (int e = 0; e < 4; e++) {
          af[mi][e] = (bf16_t)a0[e];
          af[mi][4 + e] = (bf16_t)a1[e];
        }
      }
#pragma unroll
      for (int ni = 0; ni < 4; ni++) {
        const char* Brow = (const char*)Bs + (wn * 64 + ni * 16 + l16) * 128;
        bfr[ni] = *(const bf16x8*)(Brow + (((kk2 * 4 + quad) ^ (l16 & 7)) * 16));
      }
#pragma unroll
      for (int mi = 0; mi < 4; mi++)
#pragma unroll
        for (int ni = 0; ni < 4; ni++)
          acc[mi][ni] = __builtin_amdgcn_mfma_f32_16x16x32_bf16(af[mi], bfr[ni], acc[mi][ni], 0, 0, 0);
    }
  }

#pragma unroll
  for (int ni = 0; ni < 4; ni++) {
    const int col = n0 + wn * 64 + ni * 16 + l16;
    const float bvl = bias_scale * bias[col];
    const int hh = col >> 6, d = col & (DEPTH - 1);
#pragma unroll
    for (int mi = 0; mi < 4; mi++) {
#pragma unroll
      for (int r = 0; r < 4; r++) {
        const int row = m0 + wm * 64 + mi * 16 + quad * 4 + r;
        const float val = acc[mi][ni][r] + bvl;
        const int bb = row >> 11, s = row & (SEQ - 1);
        if (z != 2) {
          Ov[((((size_t)bb * NHEAD + hh) * SEQ + s) << 6) + d] = (bf16_t)val;
        } else {
          Ov[(((size_t)bb * NHEAD + hh) * DEPTH + d) * SEQ + s] = (bf16_t)val;
        }
      }
    }
  }
}

// ---------------------------------------------------------------------------
// Output-projection GEMM (A bf16, fp32 out [M,N]), BK=64.  Grid (8,64).
// ---------------------------------------------------------------------------
__global__ __launch_bounds__(256) void gemm_wo(
    const bf16_t* __restrict__ A, const bf16_t* __restrict__ Bt,
    const float* __restrict__ bias, float* __restrict__ Ov,
    int M, int N, int K) {
  __shared__ __align__(16) bf16_t As[128 * 64];
  __shared__ __align__(16) bf16_t Bs[128 * 64];
  const int tid = threadIdx.x;
  const int lane = tid & 63;
  const int w = tid >> 6;
  const int quad = lane >> 4;
  const int l16 = lane & 15;
  const int wm = w & 1, wn = w >> 1;

  const int lin = blockIdx.x + 8 * blockIdx.y;
  const int c = lin & 7;
  const int j = lin >> 3;
  const int n0 = (j & 7) * 128;
  const int m0 = ((j >> 3) * 8 + c) * 128;

  const int r8l = lane >> 3;
  const int c8l = (lane & 7) ^ r8l;
  const bf16_t* Ag = A + (size_t)(m0 + w * 32 + r8l) * K + c8l * 8;
  const bf16_t* Bg = Bt + (size_t)(n0 + w * 32 + r8l) * K + c8l * 8;
  char* AsB = (char*)As + (w * 32) * 128;
  char* BsB = (char*)Bs + (w * 32) * 128;

  floatx4 acc[4][4] = {};

  for (int kk = 0; kk < K; kk += 64) {
    __syncthreads();
#pragma unroll
    for (int cl = 0; cl < 4; cl++) {
      GLDS16(Ag + kk + (size_t)(cl * 8) * K, AsB + cl * 8 * 128);
      GLDS16(Bg + kk + (size_t)(cl * 8) * K, BsB + cl * 8 * 128);
    }
    __syncthreads();

#pragma unroll
    for (int kk2 = 0; kk2 < 2; kk2++) {
      bf16x8 af[4], bfr[4];
#pragma unroll
      for (int mi = 0; mi < 4; mi++) {
        const char* Arow = (const char*)As + (wm * 64 + mi * 16 + l16) * 128;
        af[mi] = *(const bf16x8*)(Arow + (((kk2 * 4 + quad) ^ (l16 & 7)) * 16));
      }
#pragma unroll
      for (int ni = 0; ni < 4; ni++) {
        const char* Brow = (const char*)Bs + (wn * 64 + ni * 16 + l16) * 128;
        bfr[ni] = *(const bf16x8*)(Brow + (((kk2 * 4 + quad) ^ (l16 & 7)) * 16));
      }
#pragma unroll
      for (int mi = 0; mi < 4; mi++)
#pragma unroll
        for (int ni = 0; ni < 4; ni++)
          acc[mi][ni] = __builtin_amdgcn_mfma_f32_16x16x32_bf16(af[mi], bfr[ni], acc[mi][ni], 0, 0, 0);
    }
  }

#pragma unroll
  for (int ni = 0; ni < 4; ni++) {
    const int col = n0 + wn * 64 + ni * 16 + l16;
    const float bv = bias[col];
#pragma unroll
    for (int mi = 0; mi < 4; mi++)
#pragma unroll
      for (int r = 0; r < 4; r++) {
        const int row = m0 + wm * 64 + mi * 16 + quad * 4 + r;
        Ov[(size_t)row * N + col] = acc[mi][ni][r] + bv;
      }
  }
}

// ---------------------------------------------------------------------------
// Attention (round-9 measured structure, unchanged): swapped QK^T on
// 32x32x16 MFMA, in-register P, single-buffered two-barrier K/V staging,
// paired-float2 lsum + Lsm epilogue, sbfe keep-bit mask.
// ---------------------------------------------------------------------------
__global__ __launch_bounds__(256, 4) void attn_kernel(
    const bf16_t* __restrict__ Qh, const bf16_t* __restrict__ Kh,
    const bf16_t* __restrict__ Vt, const unsigned int* __restrict__ M32,
    bf16_t* __restrict__ O) {
  const int lane = threadIdx.x & 63;
  const int w = __builtin_amdgcn_readfirstlane(threadIdx.x >> 6);
  const int l31 = lane & 31;
  const int hi = lane >> 5;

  const int lin = blockIdx.x + 16 * blockIdx.y + 256 * blockIdx.z;  // 0..1023
  const int x8 = lin & 7;
  const int kk = lin >> 3;
  const int qt = kk & 15;               // q-tile
  const int bh = ((kk >> 4) << 3) | x8; // (b,h) pair
  const int h = bh & 15;
  const int b = bh >> 4;
  const int q0 = qt * 128;

  const bf16_t* Qb = Qh + ((size_t)b * NHEAD + h) * SEQ * DEPTH;
  const bf16_t* Kb = Kh + ((size_t)b * NHEAD + h) * SEQ * DEPTH;
  const bf16_t* Vb = Vt + ((size_t)b * NHEAD + h) * DEPTH * SEQ;
  const unsigned int* Mw =
      M32 + ((size_t)b * 64 + (qt * 4 + w)) * 32 * 64 + lane;

  __shared__ __align__(16) bf16_t Ksm[64 * 64];   // [key'][depth], swizzled
  __shared__ __align__(16) bf16_t Vsm[64 * 64];   // [depth][key], swizzled
  __shared__ float Lsm[4][32];

  // Staging: LDS dest is linear (wave base + lane*16); global source row is
  // the bit2<->bit3-permuted key (involution); col chunk is XOR-swizzled.
  const int r8 = lane >> 3;
  const int c8 = (lane & 7) ^ r8;
  const int i1 = w * 16 + r8;          // LDS row, first K call
  const int i2 = i1 + 8;               // LDS row, second K call
  const int lo1 = i1 & 31, lo2 = i2 & 31;
  const int s1 = (i1 & 32) | ((lo1 & ~12) | ((lo1 & 4) << 1) | ((lo1 & 8) >> 1));
  const int s2 = (i2 & 32) | ((lo2 & ~12) | ((lo2 & 4) << 1) | ((lo2 & 8) >> 1));
  const bf16_t* Kg1 = Kb + (size_t)s1 * DEPTH + c8 * 8;
  const bf16_t* Kg2 = Kb + (size_t)s2 * DEPTH + c8 * 8;
  const bf16_t* Vg  = Vb + (size_t)(w * 16 + r8) * SEQ + c8 * 8;
  const int woff = (w * 16) * 128;     // byte offset of wave's staging slice

  // Q fragments (B-operand): aq[t] = Q[q][t*16 + hi*8 + j], q = q0+w*32+l31
  bf16x8 aq[4];
  {
    const bf16_t* qp = Qb + (size_t)(q0 + w * 32 + l31) * DEPTH + hi * 8;
#pragma unroll
    for (int t = 0; t < 4; t++) aq[t] = *(const bf16x8*)(qp + t * 16);
  }

  floatx16 acco[2] = {};
  floatx2 l2 = {0.f, 0.f};
  const int kxor = l31 & 7;

  for (int it = 0; it < SEQ / 64; ++it) {
    const int sk = it * 64;
    const unsigned int mword = Mw[it * 64];   // prefetch before barriers
    __syncthreads();   // prior iteration's LDS reads complete
    {
      char* KsB = (char*)Ksm + woff;
      char* VsB = (char*)Vsm + woff;
      GLDS16(Kg1 + (size_t)sk * DEPTH, KsB);
      GLDS16(Kg2 + (size_t)sk * DEPTH, KsB + 8 * 128);
      GLDS16(Vg + sk, VsB);
      GLDS16(Vg + sk + (size_t)8 * SEQ, VsB + 8 * 128);
    }
    __syncthreads();   // vmcnt(0) drain: staged K/V visible

#pragma unroll
    for (int kb = 0; kb < 2; kb++) {
      // ---- QK^T: S^T tile, A = K' (permuted rows), B = Q ----
      floatx16 s = {};
      const char* Krow = (const char*)Ksm + (kb * 32 + l31) * 128;
#pragma unroll
      for (int t = 0; t < 4; t++) {
        bf16x8 kf = *(const bf16x8*)(Krow + (((2 * t + hi) ^ kxor) * 16));
        s = __builtin_amdgcn_mfma_f32_32x32x16_bf16(kf, aq[t], s, 0, 0, 0);
      }
      // ---- exp2, keep-bit mask (sbfe); P stays in registers ----
      float pv[16];
#pragma unroll
      for (int r = 0; r < 16; r++) {
        float e = __builtin_amdgcn_exp2f(s[r]);
        const int km = __builtin_amdgcn_sbfe((int)mword, kb * 16 + r, 1);
        pv[r] = __int_as_float(__float_as_int(e) & km);
      }
      // ---- paired row-sum (v_pk_add_f32) ----
#pragma unroll
      for (int r = 0; r < 8; r++)
        l2 += (floatx2){pv[2 * r], pv[2 * r + 1]};
      // ---- PV: A-frag m (= kb*2+mh) is pv[8*mh .. 8*mh+7] packed ----
#pragma unroll
      for (int mh = 0; mh < 2; mh++) {
        bf16x8 pa;
#pragma unroll
        for (int j2 = 0; j2 < 8; j2++) pa[j2] = (bf16_t)pv[mh * 8 + j2];
        const int m = kb * 2 + mh;
#pragma unroll
        for (int n = 0; n < 2; n++) {
          const char* Vrow = (const char*)Vsm + (n * 32 + l31) * 128;
          bf16x8 vf = *(const bf16x8*)(Vrow + (((2 * m + hi) ^ kxor) * 16));
          acco[n] = __builtin_amdgcn_mfma_f32_32x32x16_bf16(pa, vf, acco[n], 0, 0, 0);
        }
      }
    }
  }

  // ---- epilogue: denominator and store ----
  float lsum = l2.x + l2.y;
  float tot = lsum + __shfl_xor(lsum, 32);
  if (lane < 32) Lsm[w][l31] = __frcp_rn(tot);
  __syncthreads();

#pragma unroll
  for (int r = 0; r < 16; r++) {
    const int qr = (r & 3) + 8 * (r >> 2) + 4 * hi;   // true q-row (C layout)
    const float inv = Lsm[w][qr];
    const size_t srow = (size_t)q0 + w * 32 + qr;
#pragma unroll
    for (int n = 0; n < 2; n++) {
      const int d = h * DEPTH + n * 32 + l31;
      O[((size_t)b * SEQ + srow) * DMODEL + d] = (bf16_t)(acco[n][r] * inv);
    }
  }
}

// ---------------------------------------------------------------------------
extern "C" void kernel_launch(void* const* d_in, const int* in_sizes, int n_in,
                              void* d_out, int out_size, void* d_ws, size_t ws_size,
                              hipStream_t stream) {
  const float* q_in = (const float*)d_in[0];
  const float* k_in = (const float*)d_in[1];
  const float* v_in = (const float*)d_in[2];
  const float* m_in = (const float*)d_in[3];
  const float* Wq = (const float*)d_in[4];
  const float* bq = (const float*)d_in[5];
  const float* Wk = (const float*)d_in[6];
  const float* bk = (const float*)d_in[7];
  const float* Wv = (const float*)d_in[8];
  const float* bv = (const float*)d_in[9];
  const float* Wo = (const float*)d_in[10];
  const float* bo = (const float*)d_in[11];

  // workspace layout:
  //   [0,   8MB) : bf16 weights Wq|Wk|Wv|Wo
  //   [8,  24MB) : Obuf (bf16 attn output [B,S,DMODEL])
  //   [56, 72MB) : Qh  bf16 [B,H,S,64]
  //   [72, 88MB) : Kh  bf16 [B,H,S,64]
  //   [88,104MB) : Vth bf16 [B,H,64,S]
  //   [104,106MB): M32 keep-bit words
  char* ws = (char*)d_ws;
  const size_t MB = 1024 * 1024;
  bf16_t* wbf  = (bf16_t*)ws;
  bf16_t* Obuf = (bf16_t*)(ws + 8 * MB);
  bf16_t* Qh   = (bf16_t*)(ws + 56 * MB);
  bf16_t* Kh   = (bf16_t*)(ws + 72 * MB);
  bf16_t* Vth  = (bf16_t*)(ws + 88 * MB);
  unsigned int* M32 = (unsigned int*)(ws + 104 * MB);

  cvt_weights<<<(4 * (DMODEL * DMODEL / 4)) / 256, 256, 0, stream>>>(
      Wq, Wk, Wv, Wo, wbf);
  mask_prepack<<<(BATCH * 64 * 32 * 64) / 256, 256, 0, stream>>>(m_in, M32);

  dim3 gqkv(8, 64, 3);
  gemm_qkv<<<gqkv, 256, 0, stream>>>(q_in, k_in, v_in, wbf, bq, bk, bv,
                                     Qh, Kh, Vth);

  dim3 ga(SEQ / 128, NHEAD, BATCH);  // (16,16,4)
  attn_kernel<<<ga, 256, 0, stream>>>(Qh, Kh, Vth, M32, Obuf);

  dim3 gg(8, 64);
  gemm_wo<<<gg, 256, 0, stream>>>(
      Obuf, wbf + 3 * (size_t)DMODEL * DMODEL, bo, (float*)d_out,
      MROWS, DMODEL, DMODEL);
}

// Round 6
// 406.874 us; speedup vs baseline: 1.0183x; 1.0183x over previous
//
#include <hip/hip_runtime.h>

// ---------------------------------------------------------------------------
// Fused MultiHeadAttention forward for MI355X (gfx950).  Round 11.
//   B=4, S=2048, D_MODEL=1024, H=16, depth=64
// Round-11 changes:
//  - gemm_qkv + cvt3 reverted to the round-9-measured versions (round-10's
//    fp32-A LDS staging doubled the barrier-exposed staging bytes and cut
//    occupancy: 88->134us).
//  - mask_prepack REWRITTEN coalesced: old version read the 64MB mask with
//    lane addresses 8KB apart (16B used per 128B line).  New version: block
//    (g,b) owns 32 q-rows; phase 1 packs the 32x2048 fp32 slab into a u16
//    bit-tile in LDS with row-contiguous coalesced float4 loads; phase 2
//    assembles each output word from 4 LDS bytes.  Identical output layout.
// ---------------------------------------------------------------------------

typedef __bf16 bf16_t;
typedef __bf16 bf16x4 __attribute__((ext_vector_type(4)));
typedef __bf16 bf16x8 __attribute__((ext_vector_type(8)));
typedef float floatx2 __attribute__((ext_vector_type(2)));
typedef float floatx4 __attribute__((ext_vector_type(4)));
typedef float floatx16 __attribute__((ext_vector_type(16)));

#define DMODEL 1024
#define NHEAD  16
#define DEPTH  64
#define BATCH  4
#define SEQ    2048
#define MROWS  (BATCH * SEQ)   // 8192

// exp(s) = exp2(s*log2e); fold log2(e)/8 into Wq (and bq) so QK^T is exp2-ready
#define QSCALE 0.18033688011112042f

#define GLDS16(gaddr, laddr)                                                   \
  __builtin_amdgcn_global_load_lds(                                            \
      (__attribute__((address_space(1))) void*)(gaddr),                        \
      (__attribute__((address_space(3))) void*)(laddr), 16, 0, 0)

// ---------------------------------------------------------------------------
// fp32 -> bf16 for the 4 weight matrices, Wq pre-scaled by QSCALE.
// ---------------------------------------------------------------------------
__global__ __launch_bounds__(256) void cvt_weights(
    const float* __restrict__ w0, const float* __restrict__ w1,
    const float* __restrict__ w2, const float* __restrict__ w3,
    bf16_t* __restrict__ out) {
  const int n_per4 = (DMODEL * DMODEL) / 4;
  int idx = blockIdx.x * blockDim.x + threadIdx.x;
  int t = idx / n_per4;
  int e4 = idx - t * n_per4;
  const float* src = (t == 0) ? w0 : (t == 1) ? w1 : (t == 2) ? w2 : w3;
  const float sc = (t == 0) ? QSCALE : 1.0f;
  float4 v = ((const float4*)src)[e4];
  bf16_t* dst = out + (size_t)t * (DMODEL * DMODEL) + (size_t)e4 * 4;
  dst[0] = (bf16_t)(v.x * sc); dst[1] = (bf16_t)(v.y * sc);
  dst[2] = (bf16_t)(v.z * sc); dst[3] = (bf16_t)(v.w * sc);
}

// ---------------------------------------------------------------------------
// fp32 -> bf16 for the three activation inputs into one 48MB buffer.
// ---------------------------------------------------------------------------
__global__ __launch_bounds__(256) void cvt3(
    const float* __restrict__ q, const float* __restrict__ k,
    const float* __restrict__ v, bf16_t* __restrict__ dst) {
  const size_t n8 = (size_t)MROWS * DMODEL / 8;  // per-tensor 8-elem groups
  size_t i = (size_t)blockIdx.x * blockDim.x + threadIdx.x;  // 3*n8 threads
  int t = (int)(i / n8);
  size_t e = i - (size_t)t * n8;
  const float* src = (t == 0) ? q : (t == 1) ? k : v;
  const float4* s = (const float4*)(src + e * 8);
  float4 f0 = s[0], f1 = s[1];
  bf16x8 o;
  o[0] = (bf16_t)f0.x; o[1] = (bf16_t)f0.y; o[2] = (bf16_t)f0.z; o[3] = (bf16_t)f0.w;
  o[4] = (bf16_t)f1.x; o[5] = (bf16_t)f1.y; o[6] = (bf16_t)f1.z; o[7] = (bf16_t)f1.w;
  *(bf16x8*)(dst + i * 8) = o;
}

// ---------------------------------------------------------------------------
// Mask -> per-lane u32 KEEP-bit words (bit=1 means keep), COALESCED rewrite.
// Output layout identical to round 9:
//   word[((b*64 + g)*32 + it)*64 + lane]:
//     q = g*32 + (lane&31), hi = lane>>5
//     bit (kb*16 + r) = 1 iff m[b][q][it*64 + kb*32 + 16*(r>>3) + 8*hi +
//                                      (r&7)] == 0        (4*((r>>2)&1)+(r&3) = r&7)
// Block (g,b): phase 1 packs rows g*32..+31 (all 2048 cols) into u16 bits
// (bit (col&15) of Mb[q][col>>4]); phase 2 gathers 4 bytes per word:
//   word |= ((Mb[q][it*4+kb*2+c16] >> 8*hi) & 0xFF) << (kb*16 + c16*8)
// ---------------------------------------------------------------------------
__global__ __launch_bounds__(256) void mask_prepack(
    const float* __restrict__ m, unsigned int* __restrict__ M32) {
  __shared__ unsigned short Mb[32][132];   // 132 pad: bank-friendly rows
  const int g = blockIdx.x;                // 0..63  (32-row group)
  const int b = blockIdx.y;                // 0..3
  const int tid = threadIdx.x;
  const int lane = tid & 63;
  const int w = tid >> 6;

  const float* base = m + ((size_t)b * SEQ + g * 32) * SEQ;

  // ---- phase 1: coalesced load + bit-pack.  Wave w rows w*8..w*8+7. ----
#pragma unroll
  for (int rr = 0; rr < 8; rr++) {
    const int r = w * 8 + rr;
    const float* row = base + (size_t)r * SEQ;
#pragma unroll
    for (int half = 0; half < 2; half++) {
      const int cg = lane + half * 64;     // u16 col-group (16 cols)
      unsigned int bits = 0;
#pragma unroll
      for (int j4 = 0; j4 < 4; j4++) {
        const float4 v = *(const float4*)(row + cg * 16 + j4 * 4);
        if (v.x == 0.f) bits |= 1u << (j4 * 4 + 0);
        if (v.y == 0.f) bits |= 1u << (j4 * 4 + 1);
        if (v.z == 0.f) bits |= 1u << (j4 * 4 + 2);
        if (v.w == 0.f) bits |= 1u << (j4 * 4 + 3);
      }
      Mb[r][cg] = (unsigned short)bits;
    }
  }
  __syncthreads();

  // ---- phase 2: assemble output words (8 per thread, coalesced stores) ----
  const int q = lane & 31, hi = lane >> 5;
  unsigned int* dst = M32 + (size_t)(b * 64 + g) * 32 * 64 + lane;
#pragma unroll
  for (int ii = 0; ii < 8; ii++) {
    const int it = ii * 4 + w;
    unsigned int word = 0;
#pragma unroll
    for (int kb = 0; kb < 2; kb++)
#pragma unroll
      for (int c16 = 0; c16 < 2; c16++) {
        const unsigned int byte =
            ((unsigned int)Mb[q][it * 4 + kb * 2 + c16] >> (hi * 8)) & 0xFFu;
        word |= byte << (kb * 16 + c16 * 8);
      }
    dst[it * 64] = word;
  }
}

// ---------------------------------------------------------------------------
// Merged QKV GEMM, BK=64 (round-9 version): z selects (input, weight, bias,
// output).  256 thr / 4 waves, 128x128 tile, two-barrier single-buffer
// staging, 8x global_load_lds(16B) per stage, 32 MFMA per stage.
// z<2 -> bf16 out [B,H,S,64] (Q,K); z==2 -> bf16 out [B,H,64,S] (V^T).
// ---------------------------------------------------------------------------
__global__ __launch_bounds__(256) void gemm_qkv(
    const bf16_t* __restrict__ Abf3, const bf16_t* __restrict__ Wbf,
    const float* __restrict__ bq, const float* __restrict__ bk,
    const float* __restrict__ bv, bf16_t* __restrict__ Qh,
    bf16_t* __restrict__ Kh, bf16_t* __restrict__ Vth) {
  __shared__ __align__(16) bf16_t As[128 * 64];   // 16 KB
  __shared__ __align__(16) bf16_t Bs[128 * 64];   // 16 KB
  const int K = DMODEL;
  const int tid = threadIdx.x;
  const int lane = tid & 63;
  const int w = tid >> 6;
  const int quad = lane >> 4;
  const int l16 = lane & 15;
  const int wm = w & 1, wn = w >> 1;
  const int z = blockIdx.z;

  const bf16_t* A = Abf3 + (size_t)z * MROWS * DMODEL;
  const bf16_t* Bt = Wbf + (size_t)z * DMODEL * DMODEL;
  const float* bias = (z == 0) ? bq : (z == 1) ? bk : bv;
  const float bias_scale = (z == 0) ? QSCALE : 1.0f;
  bf16_t* Ov = (z == 0) ? Qh : (z == 1) ? Kh : Vth;

  const int lin = blockIdx.x + 8 * blockIdx.y;   // (8,64) per z
  const int c = lin & 7;
  const int j = lin >> 3;            // 0..63
  const int n0 = (j & 7) * 128;
  const int m0 = ((j >> 3) * 8 + c) * 128;

  // Staging: each GLDS16 call covers 8 rows x 128B; col chunk XOR-swizzled.
  const int r8l = lane >> 3;
  const int c8l = (lane & 7) ^ r8l;
  const bf16_t* Ag = A + (size_t)(m0 + w * 32 + r8l) * K + c8l * 8;
  const bf16_t* Bg = Bt + (size_t)(n0 + w * 32 + r8l) * K + c8l * 8;
  char* AsB = (char*)As + (w * 32) * 128;
  char* BsB = (char*)Bs + (w * 32) * 128;

  floatx4 acc[4][4] = {};

  for (int kk = 0; kk < K; kk += 64) {
    __syncthreads();
#pragma unroll
    for (int cl = 0; cl < 4; cl++) {
      GLDS16(Ag + kk + (size_t)(cl * 8) * K, AsB + cl * 8 * 128);
      GLDS16(Bg + kk + (size_t)(cl * 8) * K, BsB + cl * 8 * 128);
    }
    __syncthreads();

#pragma unroll
    for (int kk2 = 0; kk2 < 2; kk2++) {
      bf16x8 af[4], bfr[4];
#pragma unroll
      for (int mi = 0; mi < 4; mi++) {
        const char* Arow = (const char*)As + (wm * 64 + mi * 16 + l16) * 128;
        af[mi] = *(const bf16x8*)(Arow + (((kk2 * 4 + quad) ^ (l16 & 7)) * 16));
      }
#pragma unroll
      for (int ni = 0; ni < 4; ni++) {
        const char* Brow = (const char*)Bs + (wn * 64 + ni * 16 + l16) * 128;
        bfr[ni] = *(const bf16x8*)(Brow + (((kk2 * 4 + quad) ^ (l16 & 7)) * 16));
      }
#pragma unroll
      for (int mi = 0; mi < 4; mi++)
#pragma unroll
        for (int ni = 0; ni < 4; ni++)
          acc[mi][ni] = __builtin_amdgcn_mfma_f32_16x16x32_bf16(af[mi], bfr[ni], acc[mi][ni], 0, 0, 0);
    }
  }

#pragma unroll
  for (int ni = 0; ni < 4; ni++) {
    const int col = n0 + wn * 64 + ni * 16 + l16;
    const float bvl = bias_scale * bias[col];
    const int hh = col >> 6, d = col & (DEPTH - 1);
#pragma unroll
    for (int mi = 0; mi < 4; mi++) {
#pragma unroll
      for (int r = 0; r < 4; r++) {
        const int row = m0 + wm * 64 + mi * 16 + quad * 4 + r;
        const float val = acc[mi][ni][r] + bvl;
        const int bb = row >> 11, s = row & (SEQ - 1);
        if (z != 2) {
          Ov[((((size_t)bb * NHEAD + hh) * SEQ + s) << 6) + d] = (bf16_t)val;
        } else {
          Ov[(((size_t)bb * NHEAD + hh) * DEPTH + d) * SEQ + s] = (bf16_t)val;
        }
      }
    }
  }
}

// ---------------------------------------------------------------------------
// Output-projection GEMM (A bf16, fp32 out [M,N]), BK=64.  Grid (8,64).
// ---------------------------------------------------------------------------
__global__ __launch_bounds__(256) void gemm_wo(
    const bf16_t* __restrict__ A, const bf16_t* __restrict__ Bt,
    const float* __restrict__ bias, float* __restrict__ Ov,
    int M, int N, int K) {
  __shared__ __align__(16) bf16_t As[128 * 64];
  __shared__ __align__(16) bf16_t Bs[128 * 64];
  const int tid = threadIdx.x;
  const int lane = tid & 63;
  const int w = tid >> 6;
  const int quad = lane >> 4;
  const int l16 = lane & 15;
  const int wm = w & 1, wn = w >> 1;

  const int lin = blockIdx.x + 8 * blockIdx.y;
  const int c = lin & 7;
  const int j = lin >> 3;
  const int n0 = (j & 7) * 128;
  const int m0 = ((j >> 3) * 8 + c) * 128;

  const int r8l = lane >> 3;
  const int c8l = (lane & 7) ^ r8l;
  const bf16_t* Ag = A + (size_t)(m0 + w * 32 + r8l) * K + c8l * 8;
  const bf16_t* Bg = Bt + (size_t)(n0 + w * 32 + r8l) * K + c8l * 8;
  char* AsB = (char*)As + (w * 32) * 128;
  char* BsB = (char*)Bs + (w * 32) * 128;

  floatx4 acc[4][4] = {};

  for (int kk = 0; kk < K; kk += 64) {
    __syncthreads();
#pragma unroll
    for (int cl = 0; cl < 4; cl++) {
      GLDS16(Ag + kk + (size_t)(cl * 8) * K, AsB + cl * 8 * 128);
      GLDS16(Bg + kk + (size_t)(cl * 8) * K, BsB + cl * 8 * 128);
    }
    __syncthreads();

#pragma unroll
    for (int kk2 = 0; kk2 < 2; kk2++) {
      bf16x8 af[4], bfr[4];
#pragma unroll
      for (int mi = 0; mi < 4; mi++) {
        const char* Arow = (const char*)As + (wm * 64 + mi * 16 + l16) * 128;
        af[mi] = *(const bf16x8*)(Arow + (((kk2 * 4 + quad) ^ (l16 & 7)) * 16));
      }
#pragma unroll
      for (int ni = 0; ni < 4; ni++) {
        const char* Brow = (const char*)Bs + (wn * 64 + ni * 16 + l16) * 128;
        bfr[ni] = *(const bf16x8*)(Brow + (((kk2 * 4 + quad) ^ (l16 & 7)) * 16));
      }
#pragma unroll
      for (int mi = 0; mi < 4; mi++)
#pragma unroll
        for (int ni = 0; ni < 4; ni++)
          acc[mi][ni] = __builtin_amdgcn_mfma_f32_16x16x32_bf16(af[mi], bfr[ni], acc[mi][ni], 0, 0, 0);
    }
  }

#pragma unroll
  for (int ni = 0; ni < 4; ni++) {
    const int col = n0 + wn * 64 + ni * 16 + l16;
    const float bv = bias[col];
#pragma unroll
    for (int mi = 0; mi < 4; mi++)
#pragma unroll
      for (int r = 0; r < 4; r++) {
        const int row = m0 + wm * 64 + mi * 16 + quad * 4 + r;
        Ov[(size_t)row * N + col] = acc[mi][ni][r] + bv;
      }
  }
}

// ---------------------------------------------------------------------------
// Attention (round-9 measured structure, unchanged): swapped QK^T on
// 32x32x16 MFMA, in-register P, single-buffered two-barrier K/V staging,
// paired-float2 lsum + Lsm epilogue, sbfe keep-bit mask.
// ---------------------------------------------------------------------------
__global__ __launch_bounds__(256, 4) void attn_kernel(
    const bf16_t* __restrict__ Qh, const bf16_t* __restrict__ Kh,
    const bf16_t* __restrict__ Vt, const unsigned int* __restrict__ M32,
    bf16_t* __restrict__ O) {
  const int lane = threadIdx.x & 63;
  const int w = __builtin_amdgcn_readfirstlane(threadIdx.x >> 6);
  const int l31 = lane & 31;
  const int hi = lane >> 5;

  const int lin = blockIdx.x + 16 * blockIdx.y + 256 * blockIdx.z;  // 0..1023
  const int x8 = lin & 7;
  const int kk = lin >> 3;
  const int qt = kk & 15;               // q-tile
  const int bh = ((kk >> 4) << 3) | x8; // (b,h) pair
  const int h = bh & 15;
  const int b = bh >> 4;
  const int q0 = qt * 128;

  const bf16_t* Qb = Qh + ((size_t)b * NHEAD + h) * SEQ * DEPTH;
  const bf16_t* Kb = Kh + ((size_t)b * NHEAD + h) * SEQ * DEPTH;
  const bf16_t* Vb = Vt + ((size_t)b * NHEAD + h) * DEPTH * SEQ;
  const unsigned int* Mw =
      M32 + ((size_t)b * 64 + (qt * 4 + w)) * 32 * 64 + lane;

  __shared__ __align__(16) bf16_t Ksm[64 * 64];   // [key'][depth], swizzled
  __shared__ __align__(16) bf16_t Vsm[64 * 64];   // [depth][key], swizzled
  __shared__ float Lsm[4][32];

  // Staging: LDS dest is linear (wave base + lane*16); global source row is
  // the bit2<->bit3-permuted key (involution); col chunk is XOR-swizzled.
  const int r8 = lane >> 3;
  const int c8 = (lane & 7) ^ r8;
  const int i1 = w * 16 + r8;          // LDS row, first K call
  const int i2 = i1 + 8;               // LDS row, second K call
  const int lo1 = i1 & 31, lo2 = i2 & 31;
  const int s1 = (i1 & 32) | ((lo1 & ~12) | ((lo1 & 4) << 1) | ((lo1 & 8) >> 1));
  const int s2 = (i2 & 32) | ((lo2 & ~12) | ((lo2 & 4) << 1) | ((lo2 & 8) >> 1));
  const bf16_t* Kg1 = Kb + (size_t)s1 * DEPTH + c8 * 8;
  const bf16_t* Kg2 = Kb + (size_t)s2 * DEPTH + c8 * 8;
  const bf16_t* Vg  = Vb + (size_t)(w * 16 + r8) * SEQ + c8 * 8;
  const int woff = (w * 16) * 128;     // byte offset of wave's staging slice

  // Q fragments (B-operand): aq[t] = Q[q][t*16 + hi*8 + j], q = q0+w*32+l31
  bf16x8 aq[4];
  {
    const bf16_t* qp = Qb + (size_t)(q0 + w * 32 + l31) * DEPTH + hi * 8;
#pragma unroll
    for (int t = 0; t < 4; t++) aq[t] = *(const bf16x8*)(qp + t * 16);
  }

  floatx16 acco[2] = {};
  floatx2 l2 = {0.f, 0.f};
  const int kxor = l31 & 7;

  for (int it = 0; it < SEQ / 64; ++it) {
    const int sk = it * 64;
    const unsigned int mword = Mw[it * 64];   // prefetch before barriers
    __syncthreads();   // prior iteration's LDS reads complete
    {
      char* KsB = (char*)Ksm + woff;
      char* VsB = (char*)Vsm + woff;
      GLDS16(Kg1 + (size_t)sk * DEPTH, KsB);
      GLDS16(Kg2 + (size_t)sk * DEPTH, KsB + 8 * 128);
      GLDS16(Vg + sk, VsB);
      GLDS16(Vg + sk + (size_t)8 * SEQ, VsB + 8 * 128);
    }
    __syncthreads();   // vmcnt(0) drain: staged K/V visible

#pragma unroll
    for (int kb = 0; kb < 2; kb++) {
      // ---- QK^T: S^T tile, A = K' (permuted rows), B = Q ----
      floatx16 s = {};
      const char* Krow = (const char*)Ksm + (kb * 32 + l31) * 128;
#pragma unroll
      for (int t = 0; t < 4; t++) {
        bf16x8 kf = *(const bf16x8*)(Krow + (((2 * t + hi) ^ kxor) * 16));
        s = __builtin_amdgcn_mfma_f32_32x32x16_bf16(kf, aq[t], s, 0, 0, 0);
      }
      // ---- exp2, keep-bit mask (sbfe); P stays in registers ----
      float pv[16];
#pragma unroll
      for (int r = 0; r < 16; r++) {
        float e = __builtin_amdgcn_exp2f(s[r]);
        const int km = __builtin_amdgcn_sbfe((int)mword, kb * 16 + r, 1);
        pv[r] = __int_as_float(__float_as_int(e) & km);
      }
      // ---- paired row-sum (v_pk_add_f32) ----
#pragma unroll
      for (int r = 0; r < 8; r++)
        l2 += (floatx2){pv[2 * r], pv[2 * r + 1]};
      // ---- PV: A-frag m (= kb*2+mh) is pv[8*mh .. 8*mh+7] packed ----
#pragma unroll
      for (int mh = 0; mh < 2; mh++) {
        bf16x8 pa;
#pragma unroll
        for (int j2 = 0; j2 < 8; j2++) pa[j2] = (bf16_t)pv[mh * 8 + j2];
        const int m = kb * 2 + mh;
#pragma unroll
        for (int n = 0; n < 2; n++) {
          const char* Vrow = (const char*)Vsm + (n * 32 + l31) * 128;
          bf16x8 vf = *(const bf16x8*)(Vrow + (((2 * m + hi) ^ kxor) * 16));
          acco[n] = __builtin_amdgcn_mfma_f32_32x32x16_bf16(pa, vf, acco[n], 0, 0, 0);
        }
      }
    }
  }

  // ---- epilogue: denominator and store ----
  float lsum = l2.x + l2.y;
  float tot = lsum + __shfl_xor(lsum, 32);
  if (lane < 32) Lsm[w][l31] = __frcp_rn(tot);
  __syncthreads();

#pragma unroll
  for (int r = 0; r < 16; r++) {
    const int qr = (r & 3) + 8 * (r >> 2) + 4 * hi;   // true q-row (C layout)
    const float inv = Lsm[w][qr];
    const size_t srow = (size_t)q0 + w * 32 + qr;
#pragma unroll
    for (int n = 0; n < 2; n++) {
      const int d = h * DEPTH + n * 32 + l31;
      O[((size_t)b * SEQ + srow) * DMODEL + d] = (bf16_t)(acco[n][r] * inv);
    }
  }
}

// ---------------------------------------------------------------------------
extern "C" void kernel_launch(void* const* d_in, const int* in_sizes, int n_in,
                              void* d_out, int out_size, void* d_ws, size_t ws_size,
                              hipStream_t stream) {
  const float* q_in = (const float*)d_in[0];
  const float* k_in = (const float*)d_in[1];
  const float* v_in = (const float*)d_in[2];
  const float* m_in = (const float*)d_in[3];
  const float* Wq = (const float*)d_in[4];
  const float* bq = (const float*)d_in[5];
  const float* Wk = (const float*)d_in[6];
  const float* bk = (const float*)d_in[7];
  const float* Wv = (const float*)d_in[8];
  const float* bv = (const float*)d_in[9];
  const float* Wo = (const float*)d_in[10];
  const float* bo = (const float*)d_in[11];

  // workspace layout:
  //   [0,   8MB) : bf16 weights Wq|Wk|Wv|Wo
  //   [8,  56MB) : Abf3 (3 x 16MB bf16 activations); first 16MB reused as
  //                Obuf after the QKV GEMMs complete (stream-ordered)
  //   [56, 72MB) : Qh  bf16 [B,H,S,64]
  //   [72, 88MB) : Kh  bf16 [B,H,S,64]
  //   [88,104MB) : Vth bf16 [B,H,64,S]
  //   [104,106MB): M32 keep-bit words
  char* ws = (char*)d_ws;
  const size_t MB = 1024 * 1024;
  bf16_t* wbf  = (bf16_t*)ws;
  bf16_t* Abf3 = (bf16_t*)(ws + 8 * MB);
  bf16_t* Obuf = (bf16_t*)(ws + 8 * MB);   // aliases Abf3[0] (safe: QKV done)
  bf16_t* Qh   = (bf16_t*)(ws + 56 * MB);
  bf16_t* Kh   = (bf16_t*)(ws + 72 * MB);
  bf16_t* Vth  = (bf16_t*)(ws + 88 * MB);
  unsigned int* M32 = (unsigned int*)(ws + 104 * MB);

  cvt_weights<<<(4 * (DMODEL * DMODEL / 4)) / 256, 256, 0, stream>>>(
      Wq, Wk, Wv, Wo, wbf);
  cvt3<<<(3 * (MROWS * DMODEL / 8)) / 256, 256, 0, stream>>>(
      q_in, k_in, v_in, Abf3);

  dim3 gm(64, BATCH);
  mask_prepack<<<gm, 256, 0, stream>>>(m_in, M32);

  dim3 gqkv(8, 64, 3);
  gemm_qkv<<<gqkv, 256, 0, stream>>>(Abf3, wbf, bq, bk, bv, Qh, Kh, Vth);

  dim3 ga(SEQ / 128, NHEAD, BATCH);  // (16,16,4)
  attn_kernel<<<ga, 256, 0, stream>>>(Qh, Kh, Vth, M32, Obuf);

  dim3 gg(8, 64);
  gemm_wo<<<gg, 256, 0, stream>>>(
      Obuf, wbf + 3 * (size_t)DMODEL * DMODEL, bo, (float*)d_out,
      MROWS, DMODEL, DMODEL);
}